// Round 4
// baseline (336.041 us; speedup 1.0000x reference)
//
#include <hip/hip_runtime.h>

// Neural-CA update step, MI355X/gfx950.
// ca_prep: pack W1(+b1 folded as k=48)/W2 into MFMA bf16 fragments in d_ws.
// ca_update: 16x16 tile, fp32 perceive -> bf16 MFMA MLP. Per-wave LDS staging
//   (wave-private, no inner barriers). W2 frags in LDS (not regs) and no rand
//   LDS to keep unified VGPR+AGPR <= 170 -> 3 blocks/CU.
// ca_fix: 4 waves/block, one wave per worklist entry recomputes exact fp32
//   alpha for near-threshold updated pixels -> mask decisions exact.
// ca_mask: 3x3 max; zeroes dead pixels only (~0.4% of output).

#define NC 16
#define NHID 128
#define NPIX (16 * 256 * 256)
#define MG 0.04f
#define MAXFIX 65536

typedef __attribute__((ext_vector_type(8))) short s8b;   // 8 x bf16 (4 VGPRs)
typedef __attribute__((ext_vector_type(4))) float f4;

__device__ __forceinline__ unsigned short f2bf(float f) {
    union { float f; unsigned int u; } v; v.f = f;
    unsigned int r = (v.u + 0x7FFFu + ((v.u >> 16) & 1u)) >> 16;  // RNE
    return (unsigned short)r;
}
__device__ __forceinline__ unsigned int pack2(float a, float b) {
    return (unsigned int)f2bf(a) | ((unsigned int)f2bf(b) << 16);
}

// ---------------- prep: pack weights into MFMA fragment order ----------------
__global__ __launch_bounds__(256) void ca_prep(
    const float* __restrict__ W1, const float* __restrict__ b1,
    const float* __restrict__ W2, uint4* __restrict__ w1p, uint4* __restrict__ w2p)
{
    const int idx = blockIdx.x * 256 + threadIdx.x;   // grid 5 -> 1280 items
    if (idx < 1024) {
        const int fid = idx >> 6, lane = idx & 63;
        const int k0 = fid >> 3, mt = fid & 7;
        const int q = lane >> 4, i = lane & 15;
        unsigned int u[4];
        #pragma unroll
        for (int jp = 0; jp < 4; ++jp) {
            int k = k0 * 32 + q * 8 + jp * 2;
            float v0 = (k < 48) ? W1[k * 128 + mt * 16 + i] : ((k == 48) ? b1[mt * 16 + i] : 0.f);
            k++;
            float v1 = (k < 48) ? W1[k * 128 + mt * 16 + i] : ((k == 48) ? b1[mt * 16 + i] : 0.f);
            u[jp] = pack2(v0, v1);
        }
        w1p[idx] = make_uint4(u[0], u[1], u[2], u[3]);
    } else if (idx < 1280) {
        const int id2 = idx - 1024;
        const int k2 = id2 >> 6, lane = id2 & 63;
        const int q = lane >> 4, i = lane & 15;
        unsigned int u[4];
        #pragma unroll
        for (int jp = 0; jp < 4; ++jp) {
            const int k = k2 * 32 + q * 8 + jp * 2;
            u[jp] = pack2(W2[k * 16 + i], W2[(k + 1) * 16 + i]);
        }
        w2p[id2] = make_uint4(u[0], u[1], u[2], u[3]);
    }
}

// ---------------- main update kernel ----------------
__global__ __launch_bounds__(256, 3) void ca_update(
    const float* __restrict__ x, const float* __restrict__ b2,
    const float* __restrict__ rand_u, const uint4* __restrict__ w1p,
    const uint4* __restrict__ w2p, float* __restrict__ out,
    float* __restrict__ ws_alpha, unsigned char* __restrict__ ws_pre,
    unsigned int* __restrict__ fix_cnt, unsigned int* __restrict__ fix_list)
{
    __shared__ __align__(16) float xt[18 * 18 * 20];            // 25920 B
    __shared__ __align__(16) unsigned char yfs[4 * 1536];       // per-wave y frags (ya0 1KB + ya1 512B)
    __shared__ __align__(16) unsigned char hbs[4 * 4224];       // per-wave h rows, stride 264 B
    __shared__ __align__(16) uint4 w2L[256];                    // 4096 B W2 frags
    // total 53056 B -> 3 blocks/CU

    const int tid  = threadIdx.x;
    const int lane = tid & 63;
    const int li   = lane & 15;
    const int lq   = lane >> 4;
    const int wv   = tid >> 6;
    const int tx   = tid & 15, ty = tid >> 4;
    const int w0 = blockIdx.x * 16, h0 = blockIdx.y * 16, bb = blockIdx.z;

    // W1 fragments in registers (reused 4x/wave); W2 goes to LDS
    s8b w1f[2][8];
    const s8b* w1s = (const s8b*)w1p;
    #pragma unroll
    for (int k0 = 0; k0 < 2; ++k0)
        #pragma unroll
        for (int mt = 0; mt < 8; ++mt)
            w1f[k0][mt] = w1s[(k0 * 8 + mt) * 64 + lane];
    w2L[tid] = w2p[tid];
    float b2v[4];
    #pragma unroll
    for (int r = 0; r < 4; ++r) b2v[r] = b2[lq * 4 + r];

    for (int i = tid; i < 324; i += 256) {
        const int ly = i / 18, lx = i - ly * 18;
        const int gh = h0 + ly - 1, gw = w0 + lx - 1;
        float4 v0, v1, v2, v3;
        if (gh >= 0 && gh < 256 && gw >= 0 && gw < 256) {
            const float4* p = (const float4*)(x + (((size_t)bb * 256 + gh) * 256 + gw) * NC);
            v0 = p[0]; v1 = p[1]; v2 = p[2]; v3 = p[3];
        } else {
            v0 = v1 = v2 = v3 = make_float4(0.f, 0.f, 0.f, 0.f);
        }
        float4* t = (float4*)(xt + i * 20);
        t[0] = v0; t[1] = v1; t[2] = v2; t[3] = v3;
    }
    __syncthreads();

    const int o_mm = ((ty + 0) * 18 + tx + 0) * 20, o_m0 = ((ty + 0) * 18 + tx + 1) * 20, o_mp = ((ty + 0) * 18 + tx + 2) * 20;
    const int o_0m = ((ty + 1) * 18 + tx + 0) * 20, o_cc = ((ty + 1) * 18 + tx + 1) * 20, o_0p = ((ty + 1) * 18 + tx + 2) * 20;
    const int o_pm = ((ty + 2) * 18 + tx + 0) * 20, o_p0 = ((ty + 2) * 18 + tx + 1) * 20, o_pp = ((ty + 2) * 18 + tx + 2) * 20;

    // pre-life mask from ORIGINAL fp32 alpha (exact)
    {
        float am = xt[o_mm + 3];
        am = fmaxf(am, xt[o_m0 + 3]); am = fmaxf(am, xt[o_mp + 3]);
        am = fmaxf(am, xt[o_0m + 3]); am = fmaxf(am, xt[o_cc + 3]); am = fmaxf(am, xt[o_0p + 3]);
        am = fmaxf(am, xt[o_pm + 3]); am = fmaxf(am, xt[o_p0 + 3]); am = fmaxf(am, xt[o_pp + 3]);
        const size_t gpix = ((size_t)bb * 256 + h0 + ty) * 256 + (w0 + tx);
        ws_pre[gpix] = (am > 0.1f) ? (unsigned char)1 : (unsigned char)0;
    }

    // perceive -> yu[24] bf16 pairs (yu[p] = (y[2p], y[2p+1]))
    unsigned int yu[24];
    #pragma unroll
    for (int cq = 0; cq < 4; ++cq) {
        const int co = cq * 4;
        float4 vmm = *(const float4*)(xt + o_mm + co); const float* pmm = (const float*)&vmm;
        float4 vm0 = *(const float4*)(xt + o_m0 + co); const float* pm0 = (const float*)&vm0;
        float4 vmp = *(const float4*)(xt + o_mp + co); const float* pmp = (const float*)&vmp;
        float4 v0m = *(const float4*)(xt + o_0m + co); const float* p0m = (const float*)&v0m;
        float4 vcc = *(const float4*)(xt + o_cc + co); const float* pcc = (const float*)&vcc;
        float4 v0p = *(const float4*)(xt + o_0p + co); const float* p0p = (const float*)&v0p;
        float4 vpm = *(const float4*)(xt + o_pm + co); const float* ppm = (const float*)&vpm;
        float4 vp0 = *(const float4*)(xt + o_p0 + co); const float* pp0 = (const float*)&vp0;
        float4 vpp = *(const float4*)(xt + o_pp + co); const float* ppp = (const float*)&vpp;
        float yl[12];
        #pragma unroll
        for (int cc = 0; cc < 4; ++cc) {
            const float xmm = pmm[cc], xm0 = pm0[cc], xmp = pmp[cc];
            const float x0m = p0m[cc], xcc = pcc[cc], x0p = p0p[cc];
            const float xpm = ppm[cc], xp0 = pp0[cc], xpp = ppp[cc];
            yl[cc * 3 + 0] = xcc;
            yl[cc * 3 + 1] = ((xmp - xmm) + 2.f * (x0p - x0m) + (xpp - xpm)) * 0.125f;
            yl[cc * 3 + 2] = ((xpm - xmm) + 2.f * (xp0 - xm0) + (xpp - xmp)) * 0.125f;
        }
        #pragma unroll
        for (int m2 = 0; m2 < 6; ++m2) yu[cq * 6 + m2] = pack2(yl[2 * m2], yl[2 * m2 + 1]);
    }

    unsigned char* yfw = yfs + wv * 1536;
    unsigned char* hbw = hbs + wv * 4224;

    // wave-private dataflow; in-order DS per wave orders write->read
    for (int s = 0; s < 4; ++s) {
        const int t = wv * 4 + s;
        if ((ty & 3) == s) {  // quad owning row t stages its y frags
            #pragma unroll
            for (int q = 0; q < 4; ++q)
                *(uint4*)(yfw + (q * 16 + tx) * 16) = make_uint4(yu[q * 4], yu[q * 4 + 1], yu[q * 4 + 2], yu[q * 4 + 3]);
            *(uint4*)(yfw + 1024 + tx * 16)       = make_uint4(yu[16], yu[17], yu[18], yu[19]);
            *(uint4*)(yfw + 1024 + 256 + tx * 16) = make_uint4(yu[20], yu[21], yu[22], yu[23]);
        }
        const s8b ya0 = *(const s8b*)(yfw + lane * 16);
        s8b ya1;
        {
            s8b z = {0, 0, 0, 0, 0, 0, 0, 0};
            if (lane < 32) ya1 = *(const s8b*)(yfw + 1024 + lane * 16);
            else { z[0] = (lq == 2) ? (short)0x3F80 : (short)0; ya1 = z; }  // k=48 bias row = 1.0
        }
        f4 acc1[8];
        #pragma unroll
        for (int mt = 0; mt < 8; ++mt) { f4 z = {0.f, 0.f, 0.f, 0.f}; acc1[mt] = z; }
        #pragma unroll
        for (int mt = 0; mt < 8; ++mt)
            acc1[mt] = __builtin_amdgcn_mfma_f32_16x16x32_bf16(w1f[0][mt], ya0, acc1[mt], 0, 0, 0);
        #pragma unroll
        for (int mt = 0; mt < 8; ++mt)
            acc1[mt] = __builtin_amdgcn_mfma_f32_16x16x32_bf16(w1f[1][mt], ya1, acc1[mt], 0, 0, 0);
        #pragma unroll
        for (int mt = 0; mt < 8; ++mt) {
            const float hh0 = fmaxf(acc1[mt][0], 0.f), hh1 = fmaxf(acc1[mt][1], 0.f);
            const float hh2 = fmaxf(acc1[mt][2], 0.f), hh3 = fmaxf(acc1[mt][3], 0.f);
            *(uint2*)(hbw + li * 264 + mt * 32 + lq * 8) = make_uint2(pack2(hh0, hh1), pack2(hh2, hh3));
        }
        f4 acc2 = {0.f, 0.f, 0.f, 0.f};
        #pragma unroll
        for (int k2 = 0; k2 < 4; ++k2) {
            const s8b hf  = *(const s8b*)(hbw + li * 264 + k2 * 64 + lq * 16);
            const s8b w2f = *(const s8b*)((const unsigned char*)w2L + (k2 * 64 + lane) * 16);
            acc2 = __builtin_amdgcn_mfma_f32_16x16x32_bf16(w2f, hf, acc2, 0, 0, 0);
        }
        const size_t grow = ((size_t)bb * 256 + h0 + t) * 256 + w0;
        const float rv = rand_u[grow + li];
        const float um = (rv <= 0.5f) ? 1.f : 0.f;
        const float4 xc = *(const float4*)(xt + ((t + 1) * 18 + li + 1) * 20 + lq * 4);
        float4 nx;
        nx.x = fmaf(acc2[0] + b2v[0], um, xc.x);
        nx.y = fmaf(acc2[1] + b2v[1], um, xc.y);
        nx.z = fmaf(acc2[2] + b2v[2], um, xc.z);
        nx.w = fmaf(acc2[3] + b2v[3], um, xc.w);
        const size_t gp = grow + li;
        ((float4*)out)[gp * 4 + lq] = nx;
        if (lq == 0) {
            ws_alpha[gp] = nx.w;
            if (um != 0.f && fabsf(nx.w - 0.1f) <= MG) {
                unsigned int idx = atomicAdd(fix_cnt, 1u);
                if (idx < MAXFIX) fix_list[idx] = (unsigned int)gp;
            }
        }
    }
}

// ---------------- fixup: exact fp32 alpha, one wave per entry ----------------
__global__ __launch_bounds__(256) void ca_fix(
    const float* __restrict__ x, const float* __restrict__ W1,
    const float* __restrict__ b1, const float* __restrict__ W2,
    const float* __restrict__ b2,
    const unsigned int* __restrict__ fix_cnt, const unsigned int* __restrict__ fix_list,
    float* __restrict__ ws_alpha)
{
    __shared__ float ysh[4][64];
    const int wv = threadIdx.x >> 6, lane = threadIdx.x & 63;
    unsigned int n = *fix_cnt;
    if (n > MAXFIX) n = MAXFIX;
    for (unsigned int e = blockIdx.x * 4 + wv; e < n; e += gridDim.x * 4) {
        const unsigned int pix = fix_list[e];
        const int bb = pix >> 16, h = (pix >> 8) & 255, w = pix & 255;
        if (lane < 48) {
            const int c = lane / 3, j = lane - c * 3;
            float v = 0.f;
            #pragma unroll
            for (int dy = 0; dy < 3; ++dy) {
                #pragma unroll
                for (int dxx = 0; dxx < 3; ++dxx) {
                    const int hh = h + dy - 1, ww = w + dxx - 1;
                    if (hh < 0 || hh >= 256 || ww < 0 || ww >= 256) continue;
                    const float f = x[(((size_t)bb * 256 + hh) * 256 + ww) * 16 + c];
                    float wgt;
                    if (j == 0) wgt = (dy == 1 && dxx == 1) ? 1.f : 0.f;
                    else if (j == 1) wgt = ((dy == 1) ? 2.f : 1.f) * (float)(dxx - 1) * 0.125f;
                    else wgt = ((dxx == 1) ? 2.f : 1.f) * (float)(dy - 1) * 0.125f;
                    v = fmaf(f, wgt, v);
                }
            }
            ysh[wv][lane] = v;
        }
        // same-wave in-order LDS: writes above complete before reads below
        float dot = 0.f;
        #pragma unroll
        for (int t = 0; t < 2; ++t) {
            const int d = t * 64 + lane;
            float a = b1[d];
            #pragma unroll
            for (int k = 0; k < 48; ++k)
                a = fmaf(ysh[wv][k], W1[k * 128 + d], a);
            dot = fmaf(fmaxf(a, 0.f), W2[d * 16 + 3], dot);
        }
        #pragma unroll
        for (int off = 32; off > 0; off >>= 1)
            dot += __shfl_down(dot, off, 64);
        if (lane == 0)
            ws_alpha[pix] = x[(size_t)pix * 16 + 3] + dot + b2[3];
    }
}

// ---------------- mask: 3x3 max, zero dead pixels only ----------------
__global__ __launch_bounds__(256) void ca_mask(
    const float* __restrict__ alpha, const unsigned char* __restrict__ pre,
    float* __restrict__ out)
{
    __shared__ float at[18 * 20];
    const int tid = threadIdx.x;
    const int w0 = blockIdx.x * 16, h0 = blockIdx.y * 16, bb = blockIdx.z;
    for (int i = tid; i < 324; i += 256) {
        const int ly = i / 18, lx = i - ly * 18;
        const int gh = h0 + ly - 1, gw = w0 + lx - 1;
        float v = 0.f;
        if (gh >= 0 && gh < 256 && gw >= 0 && gw < 256)
            v = alpha[((size_t)bb * 256 + gh) * 256 + gw];
        at[ly * 20 + lx] = v;
    }
    __syncthreads();
    const int txx = tid & 15, tyy = tid >> 4;
    float m = at[tyy * 20 + txx];
    m = fmaxf(m, at[tyy * 20 + txx + 1]); m = fmaxf(m, at[tyy * 20 + txx + 2]);
    m = fmaxf(m, at[(tyy + 1) * 20 + txx]); m = fmaxf(m, at[(tyy + 1) * 20 + txx + 1]); m = fmaxf(m, at[(tyy + 1) * 20 + txx + 2]);
    m = fmaxf(m, at[(tyy + 2) * 20 + txx]); m = fmaxf(m, at[(tyy + 2) * 20 + txx + 1]); m = fmaxf(m, at[(tyy + 2) * 20 + txx + 2]);
    const size_t gp = ((size_t)bb * 256 + h0 + tyy) * 256 + (w0 + txx);
    const bool alive = (m > 0.1f) && pre[gp];
    if (!alive) {
        float4* po = (float4*)(out + gp * 16);
        const float4 z = make_float4(0.f, 0.f, 0.f, 0.f);
        po[0] = z; po[1] = z; po[2] = z; po[3] = z;
    }
}

extern "C" void kernel_launch(void* const* d_in, const int* in_sizes, int n_in,
                              void* d_out, int out_size, void* d_ws, size_t ws_size,
                              hipStream_t stream) {
    (void)in_sizes; (void)n_in; (void)out_size; (void)ws_size;
    const float* x  = (const float*)d_in[0];
    const float* W1 = (const float*)d_in[1];
    const float* b1 = (const float*)d_in[2];
    const float* W2 = (const float*)d_in[3];
    const float* b2 = (const float*)d_in[4];
    const float* ru = (const float*)d_in[5];
    float* out = (float*)d_out;

    char* ws = (char*)d_ws;
    float* ws_alpha       = (float*)ws;                                // 4 MiB
    unsigned char* ws_pre = (unsigned char*)(ws + (size_t)NPIX * 4);   // 1 MiB
    uint4* w1p            = (uint4*)(ws + (size_t)NPIX * 5);           // 16 KiB
    uint4* w2p            = w1p + 1024;                                // 4 KiB
    unsigned int* fix_cnt = (unsigned int*)(ws + (size_t)NPIX * 5 + 20480);
    unsigned int* fix_list= fix_cnt + 4;                               // 256 KiB

    hipMemsetAsync(fix_cnt, 0, sizeof(unsigned int), stream);
    ca_prep<<<5, 256, 0, stream>>>(W1, b1, W2, w1p, w2p);
    dim3 g(16, 16, 16);
    ca_update<<<g, 256, 0, stream>>>(x, b2, ru, w1p, w2p, out, ws_alpha, ws_pre, fix_cnt, fix_list);
    ca_fix<<<512, 256, 0, stream>>>(x, W1, b1, W2, b2, fix_cnt, fix_list, ws_alpha);
    ca_mask<<<g, 256, 0, stream>>>(ws_alpha, ws_pre, out);
}